// Round 1
// baseline (237.754 us; speedup 1.0000x reference)
//
#include <hip/hip_runtime.h>

// ---------------------------------------------------------------------------
// BasicTransformerBlock cross-frame attention, MI355X (gfx950)
// B=16, S=1024, C=320, H=8, D=40, video_length=16 -> b=1, key frame = k
// Pipeline: projQ (bf16 MFMA, scale*log2e folded) -> projK/projV (frame k only,
//           V stored transposed) -> flash attention -> projO (+bias, f32 out)
// ---------------------------------------------------------------------------

typedef short bf16x8 __attribute__((ext_vector_type(8)));
typedef float f32x4 __attribute__((ext_vector_type(4)));

constexpr int SEQ = 1024;
constexpr int CH  = 320;
constexpr int NH  = 8;
constexpr int HD  = 40;
constexpr int NB  = 16;          // batch (frames)
constexpr int KPD = 48;          // padded head dim for K/V storage
// scale = 1/sqrt(40); fold log2(e) so softmax uses exp2
constexpr float QSCALE = 0.15811388300841897f * 1.4426950408889634f;

__device__ __forceinline__ unsigned short f2bf(float f) {
  union { float f; unsigned u; } x; x.f = f;
  unsigned r = x.u + 0x7fffu + ((x.u >> 16) & 1u);   // RNE
  return (unsigned short)(r >> 16);
}

union Pack8 { bf16x8 v; unsigned short s[8]; };

__device__ __forceinline__ void cvt_store8(unsigned short* dst, const float* src) {
  float4 f0 = *(const float4*)src;
  float4 f1 = *(const float4*)(src + 4);
  Pack8 u;
  u.s[0] = f2bf(f0.x); u.s[1] = f2bf(f0.y); u.s[2] = f2bf(f0.z); u.s[3] = f2bf(f0.w);
  u.s[4] = f2bf(f1.x); u.s[5] = f2bf(f1.y); u.s[6] = f2bf(f1.z); u.s[7] = f2bf(f1.w);
  *(bf16x8*)dst = u.v;
}

// ---------------------------------------------------------------------------
// Templated projection GEMM:  Y[m,n] = sum_k A[m,k] * W[n,k]   (nn.Linear)
// MODE 0: A = hs f32 (M=16384), out = Qs bf16 [m*CH+n], value * QSCALE
// MODE 1: A = hs f32 rows k*SEQ.. (M=1024), out = Kp bf16 [h][s][KPD] (d<40)
// MODE 2: A = hs f32 rows k*SEQ.. (M=1024), out = Vt bf16 [h][KPD][s] (d<40)
// MODE 3: A = AO bf16 (M=16384), out = f32 [m*CH+n] + bias[n]
// Block 256 thr = 4 waves (2x2), tile 64x64, BK=32.
// ---------------------------------------------------------------------------
template <int MODE>
__global__ __launch_bounds__(256)
void proj_kernel(const void* __restrict__ Ap, const float* __restrict__ W,
                 void* __restrict__ outp, const float* __restrict__ bias,
                 const int* __restrict__ kptr) {
  __shared__ unsigned short Al[64][40];   // +8 pad: <=2-way bank conflicts
  __shared__ unsigned short Bl[64][40];

  const int tid = threadIdx.x;
  const int w = tid >> 6, l = tid & 63, g = l >> 4, c = l & 15;
  const int wm = w >> 1, wn = w & 1;
  const int mb = blockIdx.x, nb = blockIdx.y;

  int rowbase = 0;
  if (MODE == 1 || MODE == 2) rowbase = kptr[0] * SEQ;

  const int srow = tid >> 2;          // staging row 0..63
  const int sk   = (tid & 3) * 8;     // staging k offset 0/8/16/24

  f32x4 acc[2][2] = {};

  for (int kb = 0; kb < CH; kb += 32) {
    if (kb) __syncthreads();
    // ---- stage A tile (64 x 32)
    if (MODE == 3) {
      const unsigned short* A = (const unsigned short*)Ap;
      *(bf16x8*)&Al[srow][sk] =
          *(const bf16x8*)&A[(mb * 64 + srow) * CH + kb + sk];
    } else {
      const float* A = (const float*)Ap;
      cvt_store8(&Al[srow][sk], &A[(rowbase + mb * 64 + srow) * CH + kb + sk]);
    }
    // ---- stage B tile (64 x 32) from W rows (output cols)
    cvt_store8(&Bl[srow][sk], &W[(nb * 64 + srow) * CH + kb + sk]);
    __syncthreads();

    // ---- MFMA: each wave 32x32 = 2x2 fragments
    bf16x8 a0 = *(const bf16x8*)&Al[wm * 32 + c][g * 8];
    bf16x8 a1 = *(const bf16x8*)&Al[wm * 32 + 16 + c][g * 8];
    bf16x8 b0 = *(const bf16x8*)&Bl[wn * 32 + c][g * 8];
    bf16x8 b1 = *(const bf16x8*)&Bl[wn * 32 + 16 + c][g * 8];
    acc[0][0] = __builtin_amdgcn_mfma_f32_16x16x32_bf16(a0, b0, acc[0][0], 0, 0, 0);
    acc[0][1] = __builtin_amdgcn_mfma_f32_16x16x32_bf16(a0, b1, acc[0][1], 0, 0, 0);
    acc[1][0] = __builtin_amdgcn_mfma_f32_16x16x32_bf16(a1, b0, acc[1][0], 0, 0, 0);
    acc[1][1] = __builtin_amdgcn_mfma_f32_16x16x32_bf16(a1, b1, acc[1][1], 0, 0, 0);
  }

  // ---- epilogue: D frag lane l reg r -> row = g*4+r, col = c  [verified layout]
#pragma unroll
  for (int i = 0; i < 2; ++i)
#pragma unroll
    for (int j = 0; j < 2; ++j)
#pragma unroll
      for (int r = 0; r < 4; ++r) {
        const int m = mb * 64 + wm * 32 + i * 16 + g * 4 + r;
        const int n = nb * 64 + wn * 32 + j * 16 + c;
        const float v = acc[i][j][r];
        if (MODE == 0) {
          ((unsigned short*)outp)[m * CH + n] = f2bf(v * QSCALE);
        } else if (MODE == 1) {
          const int h = n / HD, d = n % HD;
          ((unsigned short*)outp)[(h * SEQ + m) * KPD + d] = f2bf(v);
        } else if (MODE == 2) {
          const int h = n / HD, d = n % HD;
          ((unsigned short*)outp)[(h * KPD + d) * SEQ + m] = f2bf(v);
        } else {
          ((float*)outp)[m * CH + n] = v + bias[n];
        }
      }
}

// ---------------------------------------------------------------------------
// Flash attention. Grid: 2048 blocks = (qt 0..15) + 16*(bh 0..127).
// Block 256 thr = 4 waves; wave handles 16 q-rows. KV tiles of 64 keys.
// Qs bf16 [16384][CH] (QSCALE folded); Kp [NH][SEQ][KPD]; Vt [NH][KPD][SEQ].
// ---------------------------------------------------------------------------
__global__ __launch_bounds__(256)
void attn_kernel(const unsigned short* __restrict__ Qs,
                 const unsigned short* __restrict__ Kp,
                 const unsigned short* __restrict__ Vt,
                 unsigned short* __restrict__ AO) {
  __shared__ unsigned short Klds[64][56];      // [key][d<48], 112B rows: 2-way max
  __shared__ unsigned short Vlds[48][72];      // [d][key], 144B rows
  __shared__ unsigned short Plds[4][16][72];   // per-wave P tile

  const int tid = threadIdx.x;
  const int w = tid >> 6, l = tid & 63, g = l >> 4, c = l & 15;
  const int bx = blockIdx.x;
  const int qt = bx & 15, bh = bx >> 4;
  const int b = bh >> 3, h = bh & 7;
  const int qrow0 = qt * 64 + w * 16;

  // Q fragments from global (row = lane c, k-chunk = g). d in [0,40): chunk1
  // covers d=32..63 -> only g==0 (d 32..39) is real, rest zero.
  const unsigned short* qp = Qs + (b * SEQ + qrow0 + c) * CH + h * HD;
  bf16x8 aq0 = *(const bf16x8*)&qp[g * 8];
  bf16x8 aq1 = {};
  if (g == 0) aq1 = *(const bf16x8*)&qp[32];

  f32x4 o[3] = {};
  float mrow[4], lrow[4];
#pragma unroll
  for (int r = 0; r < 4; ++r) { mrow[r] = -1e30f; lrow[r] = 0.f; }

  for (int kt = 0; kt < 16; ++kt) {
    const int kb = kt * 64;
    __syncthreads();
    // ---- stage K tile: 64 keys x 48 d (d>=40 zeroed; Kp cols 40..47 are poison)
    for (int ci = tid; ci < 384; ci += 256) {
      const int key = ci / 6;
      const int d0 = (ci - key * 6) * 8;
      bf16x8 v = {};
      if (d0 < 40) v = *(const bf16x8*)&Kp[((h << 10) + kb + key) * KPD + d0];
      *(bf16x8*)&Klds[key][d0] = v;
    }
    // ---- stage V tile transposed: 48 d x 64 keys
    for (int ci = tid; ci < 384; ci += 256) {
      const int d = ci >> 3, k0 = (ci & 7) * 8;
      bf16x8 v = {};
      if (d < 40) v = *(const bf16x8*)&Vt[(h * KPD + d) * SEQ + kb + k0];
      *(bf16x8*)&Vlds[d][k0] = v;
    }
    __syncthreads();

    // ---- QK^T: scores for 16 rows x 64 keys (4 col tiles x 2 k-chunks)
    f32x4 s[4];
#pragma unroll
    for (int jt = 0; jt < 4; ++jt) {
      const int key = jt * 16 + c;
      bf16x8 bk0 = *(const bf16x8*)&Klds[key][g * 8];
      f32x4 z = {};
      s[jt] = __builtin_amdgcn_mfma_f32_16x16x32_bf16(aq0, bk0, z, 0, 0, 0);
      bf16x8 bk1 = {};
      if (g < 2) bk1 = *(const bf16x8*)&Klds[key][32 + g * 8];  // d 32..47
      s[jt] = __builtin_amdgcn_mfma_f32_16x16x32_bf16(aq1, bk1, s[jt], 0, 0, 0);
    }

    // ---- online softmax (rows = g*4+r; reduce over 16 lanes sharing g)
    float pm[4], al[4];
#pragma unroll
    for (int r = 0; r < 4; ++r) {
      float v0 = fmaxf(fmaxf(s[0][r], s[1][r]), fmaxf(s[2][r], s[3][r]));
      v0 = fmaxf(v0, __shfl_xor(v0, 1));
      v0 = fmaxf(v0, __shfl_xor(v0, 2));
      v0 = fmaxf(v0, __shfl_xor(v0, 4));
      v0 = fmaxf(v0, __shfl_xor(v0, 8));
      const float mn = fmaxf(mrow[r], v0);
      al[r] = exp2f(mrow[r] - mn);
      mrow[r] = mn;
      pm[r] = mn;
    }
    float rs[4] = {0.f, 0.f, 0.f, 0.f};
#pragma unroll
    for (int jt = 0; jt < 4; ++jt)
#pragma unroll
      for (int r = 0; r < 4; ++r) {
        const float p = exp2f(s[jt][r] - pm[r]);
        s[jt][r] = p;
        rs[r] += p;
      }
#pragma unroll
    for (int r = 0; r < 4; ++r) {
      float t = rs[r];
      t += __shfl_xor(t, 1);
      t += __shfl_xor(t, 2);
      t += __shfl_xor(t, 4);
      t += __shfl_xor(t, 8);
      lrow[r] = lrow[r] * al[r] + t;
      o[0][r] *= al[r];
      o[1][r] *= al[r];
      o[2][r] *= al[r];
    }

    // ---- P -> LDS (bf16), same-wave region
#pragma unroll
    for (int jt = 0; jt < 4; ++jt)
#pragma unroll
      for (int r = 0; r < 4; ++r)
        Plds[w][g * 4 + r][jt * 16 + c] = f2bf(s[jt][r]);

    // ---- PV: O[16 x 48] += P[16 x 64] * V[64 x 48]
#pragma unroll
    for (int kc = 0; kc < 2; ++kc) {
      bf16x8 ap = *(const bf16x8*)&Plds[w][c][kc * 32 + g * 8];
#pragma unroll
      for (int dt = 0; dt < 3; ++dt) {
        bf16x8 bv = *(const bf16x8*)&Vlds[dt * 16 + c][kc * 32 + g * 8];
        o[dt] = __builtin_amdgcn_mfma_f32_16x16x32_bf16(ap, bv, o[dt], 0, 0, 0);
      }
    }
  }

  // ---- epilogue: normalize and write merged-head bf16 [16384][CH]
#pragma unroll
  for (int r = 0; r < 4; ++r) {
    const float inv = 1.0f / lrow[r];
    const int srow = b * SEQ + qrow0 + g * 4 + r;
#pragma unroll
    for (int dt = 0; dt < 3; ++dt) {
      const int d = dt * 16 + c;
      if (d < HD) AO[srow * CH + h * HD + d] = f2bf(o[dt][r] * inv);
    }
  }
}

// ---------------------------------------------------------------------------
extern "C" void kernel_launch(void* const* d_in, const int* in_sizes, int n_in,
                              void* d_out, int out_size, void* d_ws, size_t ws_size,
                              hipStream_t stream) {
  const float* hs = (const float*)d_in[0];
  const float* Wq = (const float*)d_in[1];
  const float* Wk = (const float*)d_in[2];
  const float* Wv = (const float*)d_in[3];
  const float* Wo = (const float*)d_in[4];
  const float* bo = (const float*)d_in[5];
  const int* kptr = (const int*)d_in[7];
  float* out = (float*)d_out;

  unsigned short* Qs = (unsigned short*)d_ws;              // 16384*320 bf16
  unsigned short* Kp = Qs + (size_t)NB * SEQ * CH;         // 8*1024*48
  unsigned short* Vt = Kp + (size_t)NH * SEQ * KPD;        // 8*48*1024
  unsigned short* AO = Vt + (size_t)NH * KPD * SEQ;        // 16384*320

  dim3 blk(256);
  proj_kernel<0><<<dim3(256, 5), blk, 0, stream>>>(hs, Wq, Qs, nullptr, nullptr);
  proj_kernel<1><<<dim3(16, 5), blk, 0, stream>>>(hs, Wk, Kp, nullptr, kptr);
  proj_kernel<2><<<dim3(16, 5), blk, 0, stream>>>(hs, Wv, Vt, nullptr, kptr);
  attn_kernel<<<dim3(2048), blk, 0, stream>>>(Qs, Kp, Vt, AO);
  proj_kernel<3><<<dim3(256, 5), blk, 0, stream>>>(AO, Wo, out, bo, nullptr);
}

// Round 3
// 171.731 us; speedup vs baseline: 1.3845x; 1.3845x over previous
//
#include <hip/hip_runtime.h>

// ---------------------------------------------------------------------------
// BasicTransformerBlock cross-frame attention, MI355X (gfx950)  — round 3
// B=16, S=1024, C=320, H=8, D=40, b=1, key frame = k
// cvt(hs,W->bf16, QSCALE into Wq) -> projQ -> projKV -> attn -> projO
// attn: swapped QK^T (S^T = K*Q^T) + key-permuted K LDS so P stays in-register
// R3 fix: ak1 addr (kr+64, was reading uninit LDS els 48..55 for g==1) + wider pad zero
// ---------------------------------------------------------------------------

typedef short bf16x8 __attribute__((ext_vector_type(8)));
typedef float f32x4 __attribute__((ext_vector_type(4)));

constexpr int SEQ = 1024;
constexpr int CH  = 320;
constexpr int NH  = 8;
constexpr int HD  = 40;
constexpr int KPD = 48;
constexpr int HS_N = 16384 * CH;      // 5,242,880
constexpr int W_N  = CH * CH;         // 102,400
// scale = 1/sqrt(40) folded with log2(e) (softmax uses exp2)
constexpr float QSCALE = 0.15811388300841897f * 1.4426950408889634f;

__device__ __forceinline__ unsigned cvtpk(float lo, float hi) {
  unsigned r;
  asm("v_cvt_pk_bf16_f32 %0, %1, %2" : "=v"(r) : "v"(lo), "v"(hi));
  return r;
}
__device__ __forceinline__ unsigned short bf1(float v) {
  return (unsigned short)cvtpk(v, v);
}

#define GLOAD16(gp, lp)                                                        \
  __builtin_amdgcn_global_load_lds(                                            \
      (const __attribute__((address_space(1))) void*)(gp),                     \
      (__attribute__((address_space(3))) void*)(lp), 16, 0, 0)

// ---------------------------------------------------------------------------
// convert pass: hs (f32->bf16), Wq*QSCALE, Wk, Wv, Wo.  8 elems/thread.
// ---------------------------------------------------------------------------
__global__ __launch_bounds__(256)
void cvt_kernel(const float* __restrict__ hs, const float* __restrict__ Wq,
                const float* __restrict__ Wk, const float* __restrict__ Wv,
                const float* __restrict__ Wo, unsigned short* __restrict__ hsb,
                unsigned short* __restrict__ wqb, unsigned short* __restrict__ wkb,
                unsigned short* __restrict__ wvb, unsigned short* __restrict__ wob) {
  const int i8 = (blockIdx.x * 256 + threadIdx.x) * 8;
  const float* src; unsigned short* dst; int off; float sc = 1.f;
  if (i8 < HS_N) { src = hs; dst = hsb; off = i8; }
  else {
    int j = i8 - HS_N;
    if (j < W_N)            { src = Wq; dst = wqb; off = j;           sc = QSCALE; }
    else if (j < 2 * W_N)   { src = Wk; dst = wkb; off = j - W_N; }
    else if (j < 3 * W_N)   { src = Wv; dst = wvb; off = j - 2 * W_N; }
    else                    { src = Wo; dst = wob; off = j - 3 * W_N; }
  }
  float4 f0 = *(const float4*)(src + off);
  float4 f1 = *(const float4*)(src + off + 4);
  union { bf16x8 v; unsigned u[4]; } o;
  o.u[0] = cvtpk(f0.x * sc, f0.y * sc);
  o.u[1] = cvtpk(f0.z * sc, f0.w * sc);
  o.u[2] = cvtpk(f1.x * sc, f1.y * sc);
  o.u[3] = cvtpk(f1.z * sc, f1.w * sc);
  *(bf16x8*)(dst + off) = o.v;
}

// ---------------------------------------------------------------------------
// bf16 projection GEMM, tile 64x64, BK=64, 4 waves (2x2), global_load_lds +
// XOR-swizzled LDS (chunk ^= row&7 over 8x16B rows -> 2-way max on reads).
// MODE 0: out bf16 [m][CH]                 (Q; QSCALE already in Wq)
// MODE 1: rows k*SEQ..; z=0 -> Kp [h][s][KPD], z=1 -> Vt [h][KPD][s]
// MODE 3: out f32 [m][CH] + bias
// ---------------------------------------------------------------------------
__device__ __forceinline__ bf16x8 lds_frag(const unsigned short (*T)[64],
                                           int row, int lc) {
  return *(const bf16x8*)((const char*)T + row * 128 + ((lc ^ (row & 7)) << 4));
}

template <int MODE>
__global__ __launch_bounds__(256)
void proj2(const unsigned short* __restrict__ A, const unsigned short* __restrict__ W,
           void* __restrict__ outp, const float* __restrict__ bias,
           const int* __restrict__ kptr, const unsigned short* __restrict__ W2,
           void* __restrict__ out2) {
  __shared__ unsigned short Al[64][64];
  __shared__ unsigned short Bl[64][64];

  const int tid = threadIdx.x;
  const int w = tid >> 6, l = tid & 63, g = l >> 4, c = l & 15;
  const int wm = w >> 1, wn = w & 1;
  const int mb = blockIdx.x, nb = blockIdx.y;

  const unsigned short* Wp = W;
  void* op = outp;
  bool isV = false;
  if (MODE == 1 && blockIdx.z == 1) { Wp = W2; op = out2; isV = true; }
  const int rowbase = (MODE == 1) ? kptr[0] * SEQ : 0;

  // staging: row = li>>3, phys chunk = li&7, logical chunk = pc ^ (row&7)
  // (source pre-swizzle, linear LDS dest -> rule #21 satisfied)
  const int rA0 = tid >> 3, pcA = tid & 7;
  const int rA1 = rA0 + 32;
  const int lc0 = pcA ^ (rA0 & 7);
  const int lc1 = pcA ^ (rA1 & 7);
  const unsigned short* aBase = A + (size_t)(rowbase + mb * 64) * CH;
  const unsigned short* wBase = Wp + (size_t)(nb * 64) * CH;
  unsigned short* ldsA0 = &Al[0][0] + tid * 8;
  unsigned short* ldsA1 = &Al[0][0] + (tid + 256) * 8;
  unsigned short* ldsB0 = &Bl[0][0] + tid * 8;
  unsigned short* ldsB1 = &Bl[0][0] + (tid + 256) * 8;

  f32x4 acc[2][2] = {};

  for (int kb = 0; kb < CH; kb += 64) {
    if (kb) __syncthreads();
    GLOAD16(aBase + rA0 * CH + kb + lc0 * 8, ldsA0);
    GLOAD16(aBase + rA1 * CH + kb + lc1 * 8, ldsA1);
    GLOAD16(wBase + rA0 * CH + kb + lc0 * 8, ldsB0);
    GLOAD16(wBase + rA1 * CH + kb + lc1 * 8, ldsB1);
    __syncthreads();
#pragma unroll
    for (int kc = 0; kc < 2; ++kc) {
      bf16x8 a0 = lds_frag(Al, wm * 32 + c,      kc * 4 + g);
      bf16x8 a1 = lds_frag(Al, wm * 32 + 16 + c, kc * 4 + g);
      bf16x8 b0 = lds_frag(Bl, wn * 32 + c,      kc * 4 + g);
      bf16x8 b1 = lds_frag(Bl, wn * 32 + 16 + c, kc * 4 + g);
      acc[0][0] = __builtin_amdgcn_mfma_f32_16x16x32_bf16(a0, b0, acc[0][0], 0, 0, 0);
      acc[0][1] = __builtin_amdgcn_mfma_f32_16x16x32_bf16(a0, b1, acc[0][1], 0, 0, 0);
      acc[1][0] = __builtin_amdgcn_mfma_f32_16x16x32_bf16(a1, b0, acc[1][0], 0, 0, 0);
      acc[1][1] = __builtin_amdgcn_mfma_f32_16x16x32_bf16(a1, b1, acc[1][1], 0, 0, 0);
    }
  }

  // epilogue: D lane (g,c) reg r -> row = g*4+r, col = c
#pragma unroll
  for (int i = 0; i < 2; ++i)
#pragma unroll
    for (int j = 0; j < 2; ++j)
#pragma unroll
      for (int r = 0; r < 4; ++r) {
        const int m = mb * 64 + wm * 32 + i * 16 + g * 4 + r;
        const int n = nb * 64 + wn * 32 + j * 16 + c;
        const float v = acc[i][j][r];
        if (MODE == 0) {
          ((unsigned short*)op)[(size_t)m * CH + n] = bf1(v);
        } else if (MODE == 1) {
          const int h = n / HD, d = n % HD;
          if (!isV)
            ((unsigned short*)op)[(size_t)(h * SEQ + m) * KPD + d] = bf1(v);
          else
            ((unsigned short*)op)[(size_t)(h * KPD + d) * SEQ + m] = bf1(v);
        } else {
          ((float*)op)[(size_t)m * CH + n] = v + bias[n];
        }
      }
}

// ---------------------------------------------------------------------------
// Flash attention, swapped operands. Grid 2048 = (qt 0..15) | (bh<<4).
// Block 256 = 4 waves; wave owns 16 q-rows (lane c = q-row). KV tile = 64.
// K staged at permuted LDS slot s: phys key k(s) = (s&35)|((s&12)<<1)|((s&16)>>2)
// => after softmax, lane's p regs ARE the PV B-fragment (no shuffles, no P LDS).
// ---------------------------------------------------------------------------
__global__ __launch_bounds__(256)
void attn2(const unsigned short* __restrict__ Qs,
           const unsigned short* __restrict__ Kp,
           const unsigned short* __restrict__ Vt,
           unsigned short* __restrict__ AO) {
  __shared__ unsigned short Klds[64][56];   // rows 112B: 2-way max on reads
  __shared__ unsigned short Vlds[48][72];   // rows 144B: 2-way max

  const int tid = threadIdx.x;
  const int w = tid >> 6, l = tid & 63, g = l >> 4, c = l & 15;
  const int qt = blockIdx.x & 15, bh = blockIdx.x >> 4;
  const int b = bh >> 3, h = bh & 7;
  const int qrow0 = qt * 64 + w * 16;

  // ---- staging descriptors (computed once)
  // K: 320 real chunks (64 slot-rows x 5): rho = ci/5, d0 = (ci%5)*8
  const int ciK1 = tid + 256;
  const int rho0 = tid / 5,  ch0 = tid - rho0 * 5;
  const int rho1 = ciK1 / 5, ch1 = ciK1 - rho1 * 5;
  const int key0 = (rho0 & 35) | ((rho0 & 12) << 1) | ((rho0 & 16) >> 2);
  const int key1 = ((rho1 & 63) & 35) | (((rho1 & 63) & 12) << 1) | (((rho1 & 63) & 16) >> 2);
  const unsigned short* gK0 = Kp + (size_t)((h << 10) + key0) * KPD + ch0 * 8;
  const unsigned short* gK1 = Kp + (size_t)((h << 10) + key1) * KPD + ch1 * 8;
  unsigned short* lK0 = &Klds[rho0][ch0 * 8];
  unsigned short* lK1 = &Klds[rho1 & 63][ch1 * 8];
  // V: 320 real chunks (40 d-rows x 8): d = ci>>3, k0 = (ci&7)*8
  const int dV0 = tid >> 3, k0V = (tid & 7) * 8;
  const int dV1 = dV0 + 32;
  const unsigned short* gV0 = Vt + (size_t)(h * KPD + dV0) * SEQ + k0V;
  const unsigned short* gV1 = Vt + (size_t)(h * KPD + (dV1 & 47)) * SEQ + k0V;
  unsigned short* lV0 = &Vlds[dV0][k0V];
  unsigned short* lV1 = &Vlds[dV1 & 47][k0V];
  const bool has1 = (tid < 64);

  // ---- pre-zero pads (never overwritten by staging):
  // Klds[*][40..55] (els 48..55 exist because row stride is 56) and Vlds[40..47][*]
  if (tid < 128) {
    *(bf16x8*)&Klds[tid >> 1][40 + (tid & 1) * 8] = (bf16x8){};
  } else if (tid < 192) {
    const int t = tid - 128;
    *(bf16x8*)&Vlds[40 + (t >> 3)][(t & 7) * 8] = (bf16x8){};
  }

  // ---- Q fragments (B-operand: lane holds Q[qrow=c][d chunk g])
  const unsigned short* qp = Qs + (size_t)(b * SEQ + qrow0 + c) * CH + h * HD;
  bf16x8 aq0 = *(const bf16x8*)(qp + g * 8);
  bf16x8 aq1 = {};
  if (g == 0) aq1 = *(const bf16x8*)(qp + 32);

  f32x4 o0 = {}, o1 = {}, o2 = {};
  float m = -3e38f, lsum = 0.f;

  // prologue loads (tile 0)
  bf16x8 rk0 = *(const bf16x8*)gK0, rv0 = *(const bf16x8*)gV0;
  bf16x8 rk1 = {}, rv1 = {};
  if (has1) { rk1 = *(const bf16x8*)gK1; rv1 = *(const bf16x8*)gV1; }

  for (int kt = 0; kt < 16; ++kt) {
    __syncthreads();                       // prev compute done with LDS
    *(bf16x8*)lK0 = rk0; *(bf16x8*)lV0 = rv0;
    if (has1) { *(bf16x8*)lK1 = rk1; *(bf16x8*)lV1 = rv1; }
    __syncthreads();
    // prefetch next tile (overlaps compute below)
    if (kt < 15) {
      gK0 += 64 * KPD; gV0 += 64;
      rk0 = *(const bf16x8*)gK0; rv0 = *(const bf16x8*)gV0;
      if (has1) {
        gK1 += 64 * KPD; gV1 += 64;
        rk1 = *(const bf16x8*)gK1; rv1 = *(const bf16x8*)gV1;
      }
    }

    // ---- S^T = K * Q^T : A-frag = Klds slot row (jt*16 + c), d-chunk g
    f32x4 p0, p1, p2, p3;
    {
      const char* kbase = (const char*)&Klds[0][0] + (size_t)c * 112 + (g << 4);
      f32x4 z = {};
#pragma unroll
      for (int jt = 0; jt < 4; ++jt) {
        const char* kr = kbase + jt * 16 * 112;
        bf16x8 ak0 = *(const bf16x8*)kr;
        bf16x8 ak1 = {};
        if (g < 2) ak1 = *(const bf16x8*)(kr + 64);   // el 32+g*8 (kr carries g*16)
        f32x4 s = __builtin_amdgcn_mfma_f32_16x16x32_bf16(ak0, aq0, z, 0, 0, 0);
        s = __builtin_amdgcn_mfma_f32_16x16x32_bf16(ak1, aq1, s, 0, 0, 0);
        if (jt == 0) p0 = s; else if (jt == 1) p1 = s;
        else if (jt == 2) p2 = s; else p3 = s;
      }
    }

    // ---- per-lane softmax (lane owns q-row c; peers at lanes ^16, ^32)
    float vmax = fmaxf(fmaxf(fmaxf(p0[0], p0[1]), fmaxf(p0[2], p0[3])),
                       fmaxf(fmaxf(p1[0], p1[1]), fmaxf(p1[2], p1[3])));
    vmax = fmaxf(vmax, fmaxf(fmaxf(fmaxf(p2[0], p2[1]), fmaxf(p2[2], p2[3])),
                             fmaxf(fmaxf(p3[0], p3[1]), fmaxf(p3[2], p3[3]))));
    vmax = fmaxf(vmax, __shfl_xor(vmax, 16));
    vmax = fmaxf(vmax, __shfl_xor(vmax, 32));
    const float mn = fmaxf(m, vmax);
    const float al = exp2f(m - mn);
    m = mn;
    float rs = 0.f;
#pragma unroll
    for (int r = 0; r < 4; ++r) { p0[r] = exp2f(p0[r] - mn); rs += p0[r]; }
#pragma unroll
    for (int r = 0; r < 4; ++r) { p1[r] = exp2f(p1[r] - mn); rs += p1[r]; }
#pragma unroll
    for (int r = 0; r < 4; ++r) { p2[r] = exp2f(p2[r] - mn); rs += p2[r]; }
#pragma unroll
    for (int r = 0; r < 4; ++r) { p3[r] = exp2f(p3[r] - mn); rs += p3[r]; }
    rs += __shfl_xor(rs, 16);
    rs += __shfl_xor(rs, 32);
    lsum = lsum * al + rs;
    o0 *= al; o1 *= al; o2 *= al;

    // ---- pack P: lane's regs are already the PV B-fragment (key-permuted LDS)
    union { bf16x8 v; unsigned u[4]; } pb0, pb1;
    pb0.u[0] = cvtpk(p0[0], p0[1]); pb0.u[1] = cvtpk(p0[2], p0[3]);
    pb0.u[2] = cvtpk(p1[0], p1[1]); pb0.u[3] = cvtpk(p1[2], p1[3]);
    pb1.u[0] = cvtpk(p2[0], p2[1]); pb1.u[1] = cvtpk(p2[2], p2[3]);
    pb1.u[2] = cvtpk(p3[0], p3[1]); pb1.u[3] = cvtpk(p3[2], p3[3]);

    // ---- O^T += V^T * P^T  (A-frag = Vlds row d = dt*16+c, key chunk g)
    {
      const char* vbase = (const char*)&Vlds[0][0] + (size_t)c * 144 + (g << 4);
      bf16x8 av;
      av = *(const bf16x8*)(vbase);
      o0 = __builtin_amdgcn_mfma_f32_16x16x32_bf16(av, pb0.v, o0, 0, 0, 0);
      av = *(const bf16x8*)(vbase + 16 * 144);
      o1 = __builtin_amdgcn_mfma_f32_16x16x32_bf16(av, pb0.v, o1, 0, 0, 0);
      av = *(const bf16x8*)(vbase + 32 * 144);
      o2 = __builtin_amdgcn_mfma_f32_16x16x32_bf16(av, pb0.v, o2, 0, 0, 0);
      av = *(const bf16x8*)(vbase + 64);
      o0 = __builtin_amdgcn_mfma_f32_16x16x32_bf16(av, pb1.v, o0, 0, 0, 0);
      av = *(const bf16x8*)(vbase + 64 + 16 * 144);
      o1 = __builtin_amdgcn_mfma_f32_16x16x32_bf16(av, pb1.v, o1, 0, 0, 0);
      av = *(const bf16x8*)(vbase + 64 + 32 * 144);
      o2 = __builtin_amdgcn_mfma_f32_16x16x32_bf16(av, pb1.v, o2, 0, 0, 0);
    }
  }

  // ---- epilogue: lane owns q-row c; O^T row = d
  const float inv = 1.0f / lsum;
  unsigned short* orow = AO + (size_t)(b * SEQ + qrow0 + c) * CH + h * HD;
  union { uint2 q; unsigned u[2]; } st;
  st.u[0] = cvtpk(o0[0] * inv, o0[1] * inv);
  st.u[1] = cvtpk(o0[2] * inv, o0[3] * inv);
  *(uint2*)(orow + g * 4) = st.q;
  st.u[0] = cvtpk(o1[0] * inv, o1[1] * inv);
  st.u[1] = cvtpk(o1[2] * inv, o1[3] * inv);
  *(uint2*)(orow + 16 + g * 4) = st.q;
  if (g < 2) {
    st.u[0] = cvtpk(o2[0] * inv, o2[1] * inv);
    st.u[1] = cvtpk(o2[2] * inv, o2[3] * inv);
    *(uint2*)(orow + 32 + g * 4) = st.q;
  }
}

// ---------------------------------------------------------------------------
extern "C" void kernel_launch(void* const* d_in, const int* in_sizes, int n_in,
                              void* d_out, int out_size, void* d_ws, size_t ws_size,
                              hipStream_t stream) {
  const float* hs = (const float*)d_in[0];
  const float* Wq = (const float*)d_in[1];
  const float* Wk = (const float*)d_in[2];
  const float* Wv = (const float*)d_in[3];
  const float* Wo = (const float*)d_in[4];
  const float* bo = (const float*)d_in[5];
  const int* kptr = (const int*)d_in[7];
  float* out = (float*)d_out;

  unsigned short* hsb = (unsigned short*)d_ws;
  unsigned short* wqb = hsb + HS_N;
  unsigned short* wkb = wqb + W_N;
  unsigned short* wvb = wkb + W_N;
  unsigned short* wob = wvb + W_N;
  unsigned short* Qs  = wob + W_N;
  unsigned short* Kp  = Qs + HS_N;                 // [8][1024][48]
  unsigned short* Vt  = Kp + NH * SEQ * KPD;       // [8][48][1024]
  unsigned short* AO  = Vt + NH * KPD * SEQ;       // [16384][320]

  dim3 blk(256);
  cvt_kernel<<<dim3((HS_N + 4 * W_N) / 2048), blk, 0, stream>>>(
      hs, Wq, Wk, Wv, Wo, hsb, wqb, wkb, wvb, wob);
  proj2<0><<<dim3(256, 5), blk, 0, stream>>>(hsb, wqb, Qs, nullptr, nullptr, nullptr, nullptr);
  proj2<1><<<dim3(16, 5, 2), blk, 0, stream>>>(hsb, wkb, Kp, nullptr, kptr, wvb, Vt);
  attn2<<<dim3(2048), blk, 0, stream>>>(Qs, Kp, Vt, AO);
  proj2<3><<<dim3(256, 5), blk, 0, stream>>>(AO, wob, out, bo, nullptr, nullptr, nullptr);
}

// Round 4
// 164.910 us; speedup vs baseline: 1.4417x; 1.0414x over previous
//
#include <hip/hip_runtime.h>

// ---------------------------------------------------------------------------
// BasicTransformerBlock cross-frame attention, MI355X (gfx950)  — round 4
// B=16, S=1024, C=320, H=8, D=40, b=1, key frame = k
// cvt -> projQ(128-tile) -> projKV(64-tile) -> attn(8-wave, swizzled LDS,
// defer-max, setprio) -> projO(128-tile)
// ---------------------------------------------------------------------------

typedef short bf16x8 __attribute__((ext_vector_type(8)));
typedef float f32x4 __attribute__((ext_vector_type(4)));

constexpr int SEQ = 1024;
constexpr int CH  = 320;
constexpr int NH  = 8;
constexpr int HD  = 40;
constexpr int KPD = 48;
constexpr int HS_N = 16384 * CH;      // 5,242,880
constexpr int W_N  = CH * CH;         // 102,400
// scale = 1/sqrt(40) folded with log2(e) (softmax uses exp2)
constexpr float QSCALE = 0.15811388300841897f * 1.4426950408889634f;

__device__ __forceinline__ unsigned cvtpk(float lo, float hi) {
  unsigned r;
  asm("v_cvt_pk_bf16_f32 %0, %1, %2" : "=v"(r) : "v"(lo), "v"(hi));
  return r;
}
__device__ __forceinline__ unsigned short bf1(float v) {
  return (unsigned short)cvtpk(v, v);
}

#define GLOAD16(gp, lp)                                                        \
  __builtin_amdgcn_global_load_lds(                                            \
      (const __attribute__((address_space(1))) void*)(gp),                     \
      (__attribute__((address_space(3))) void*)(lp), 16, 0, 0)

// ---------------------------------------------------------------------------
// convert pass: hs (f32->bf16), Wq*QSCALE, Wk, Wv, Wo.  8 elems/thread.
// ---------------------------------------------------------------------------
__global__ __launch_bounds__(256)
void cvt_kernel(const float* __restrict__ hs, const float* __restrict__ Wq,
                const float* __restrict__ Wk, const float* __restrict__ Wv,
                const float* __restrict__ Wo, unsigned short* __restrict__ hsb,
                unsigned short* __restrict__ wqb, unsigned short* __restrict__ wkb,
                unsigned short* __restrict__ wvb, unsigned short* __restrict__ wob) {
  const int i8 = (blockIdx.x * 256 + threadIdx.x) * 8;
  const float* src; unsigned short* dst; int off; float sc = 1.f;
  if (i8 < HS_N) { src = hs; dst = hsb; off = i8; }
  else {
    int j = i8 - HS_N;
    if (j < W_N)            { src = Wq; dst = wqb; off = j;           sc = QSCALE; }
    else if (j < 2 * W_N)   { src = Wk; dst = wkb; off = j - W_N; }
    else if (j < 3 * W_N)   { src = Wv; dst = wvb; off = j - 2 * W_N; }
    else                    { src = Wo; dst = wob; off = j - 3 * W_N; }
  }
  float4 f0 = *(const float4*)(src + off);
  float4 f1 = *(const float4*)(src + off + 4);
  union { bf16x8 v; unsigned u[4]; } o;
  o.u[0] = cvtpk(f0.x * sc, f0.y * sc);
  o.u[1] = cvtpk(f0.z * sc, f0.w * sc);
  o.u[2] = cvtpk(f1.x * sc, f1.y * sc);
  o.u[3] = cvtpk(f1.z * sc, f1.w * sc);
  *(bf16x8*)(dst + off) = o.v;
}

// ---------------------------------------------------------------------------
// bf16 projection GEMM, tile BMx64, BK=64, 4 waves (wave = BM/2 x 32 out),
// global_load_lds + XOR-swizzled LDS (128B rows, chunk ^= row&7).
// MODE 0: out bf16 [m][CH]                 (Q; QSCALE already in Wq)
// MODE 1: rows k*SEQ..; z=0 -> Kp [h][s][KPD], z=1 -> Vt [h][KPD][s]
// MODE 3: out f32 [m][CH] + bias
// ---------------------------------------------------------------------------
__device__ __forceinline__ bf16x8 lds_frag(const unsigned short* T, int row, int lc) {
  return *(const bf16x8*)((const char*)T + row * 128 + ((lc ^ (row & 7)) << 4));
}

template <int MODE, int BM>
__global__ __launch_bounds__(256)
void proj3(const unsigned short* __restrict__ A, const unsigned short* __restrict__ W,
           void* __restrict__ outp, const float* __restrict__ bias,
           const int* __restrict__ kptr, const unsigned short* __restrict__ W2,
           void* __restrict__ out2) {
  __shared__ unsigned short Al[BM][64];
  __shared__ unsigned short Bl[64][64];
  constexpr int NI = BM / 32;           // m-frags per wave

  const int tid = threadIdx.x;
  const int w = tid >> 6, l = tid & 63, g = l >> 4, c = l & 15;
  const int wm = w >> 1, wn = w & 1;
  const int mb = blockIdx.x, nb = blockIdx.y;

  const unsigned short* Wp = W;
  void* op = outp;
  bool isV = false;
  if (MODE == 1 && blockIdx.z == 1) { Wp = W2; op = out2; isV = true; }
  const int rowbase = (MODE == 1) ? kptr[0] * SEQ : 0;

  const int sr = tid >> 3, pc = tid & 7;
  const unsigned short* aBase = A + (size_t)(rowbase + mb * BM) * CH;
  const unsigned short* wBase = Wp + (size_t)(nb * 64) * CH;

  f32x4 acc[NI][2] = {};

  for (int kb = 0; kb < CH; kb += 64) {
    if (kb) __syncthreads();
#pragma unroll
    for (int q = 0; q < BM / 32; ++q) {
      const int row = q * 32 + sr;
      const int lc = pc ^ (row & 7);
      GLOAD16(aBase + (size_t)row * CH + kb + lc * 8,
              (unsigned short*)Al + (q * 256 + tid) * 8);
    }
#pragma unroll
    for (int q = 0; q < 2; ++q) {
      const int row = q * 32 + sr;
      const int lc = pc ^ (row & 7);
      GLOAD16(wBase + (size_t)row * CH + kb + lc * 8,
              (unsigned short*)Bl + (q * 256 + tid) * 8);
    }
    __syncthreads();
#pragma unroll
    for (int kc = 0; kc < 2; ++kc) {
      bf16x8 b0 = lds_frag(&Bl[0][0], wn * 32 + c,      kc * 4 + g);
      bf16x8 b1 = lds_frag(&Bl[0][0], wn * 32 + 16 + c, kc * 4 + g);
#pragma unroll
      for (int i = 0; i < NI; ++i) {
        bf16x8 af = lds_frag(&Al[0][0], wm * (BM / 2) + i * 16 + c, kc * 4 + g);
        acc[i][0] = __builtin_amdgcn_mfma_f32_16x16x32_bf16(af, b0, acc[i][0], 0, 0, 0);
        acc[i][1] = __builtin_amdgcn_mfma_f32_16x16x32_bf16(af, b1, acc[i][1], 0, 0, 0);
      }
    }
  }

  // epilogue: D lane (g,c) reg r -> row = g*4+r, col = c
#pragma unroll
  for (int i = 0; i < NI; ++i)
#pragma unroll
    for (int j = 0; j < 2; ++j)
#pragma unroll
      for (int r = 0; r < 4; ++r) {
        const int m = mb * BM + wm * (BM / 2) + i * 16 + g * 4 + r;
        const int n = nb * 64 + wn * 32 + j * 16 + c;
        const float v = acc[i][j][r];
        if (MODE == 0) {
          ((unsigned short*)op)[(size_t)m * CH + n] = bf1(v);
        } else if (MODE == 1) {
          const int h = n / HD, d = n % HD;
          if (!isV)
            ((unsigned short*)op)[(size_t)(h * SEQ + m) * KPD + d] = bf1(v);
          else
            ((unsigned short*)op)[(size_t)(h * KPD + d) * SEQ + m] = bf1(v);
        } else {
          ((float*)op)[(size_t)m * CH + n] = v + bias[n];
        }
      }
}

// ---------------------------------------------------------------------------
// Flash attention. Grid 1024 = (qt 0..7) | (bh<<3).  Block 512 = 8 waves;
// wave owns 16 q-rows (lane c = q-row). KV tile = 64 keys.
// K staged at permuted slot s: phys key = (s&35)|((s&12)<<1)|((s&16)>>2)
// => after softmax, lane's p regs ARE the PV B-fragment.
// LDS rows 128B, chunk XOR-swizzled by row&7 -> conflict-free ds_read_b128.
// ---------------------------------------------------------------------------
__global__ __launch_bounds__(512)
void attn3(const unsigned short* __restrict__ Qs,
           const unsigned short* __restrict__ Kp,
           const unsigned short* __restrict__ Vt,
           unsigned short* __restrict__ AO) {
  __shared__ unsigned short Klds[64][64];
  __shared__ unsigned short Vlds[48][64];

  const int tid = threadIdx.x;
  const int w = tid >> 6, l = tid & 63, g = l >> 4, c = l & 15;
  const int qt = blockIdx.x & 7, bh = blockIdx.x >> 3;
  const int b = bh >> 3, h = bh & 7;
  const int qrow0 = qt * 128 + w * 16;

  // ---- staging descriptors: (slot, pc) = (tid>>3, tid&7), lc = pc^(slot&7)
  const int slot = tid >> 3, pc = tid & 7;
  const int lcK = pc ^ (slot & 7);
  const int key = (slot & 35) | ((slot & 12) << 1) | ((slot & 16) >> 2);
  const bool kReal = (lcK < 5);                    // d<40 real; rest zero
  const unsigned short* gK = Kp + (size_t)((h << 10) + key) * KPD + lcK * 8;
  unsigned short* lK = &Klds[slot][pc * 8];
  const bool vAct = tid < 384;                     // 48 rows x 8 chunks
  const int vrow = vAct ? slot : 0;
  const bool vReal = vAct && (slot < 40);          // d<40 real; rows 40..47 zero
  const unsigned short* gV = Vt + (size_t)(h * KPD + vrow) * SEQ + (pc ^ (vrow & 7)) * 8;
  unsigned short* lV = &Vlds[vrow][pc * 8];

  // ---- Q fragments (B-operand: lane holds Q[qrow=c][d chunk g])
  const unsigned short* qp = Qs + (size_t)(b * SEQ + qrow0 + c) * CH + h * HD;
  bf16x8 aq0 = *(const bf16x8*)(qp + g * 8);
  bf16x8 aq1 = {};
  if (g == 0) aq1 = *(const bf16x8*)(qp + 32);

  f32x4 o0 = {}, o1 = {}, o2 = {};
  float m = -3e38f, lsum = 0.f;

  // prologue loads (tile 0)
  bf16x8 rk = {}, rv = {};
  if (kReal) rk = *(const bf16x8*)gK;
  if (vReal) rv = *(const bf16x8*)gV;

  const int sw = c & 7;
  const char* kROb = (const char*)&Klds[0][0] + c * 128;
  const char* vROb = (const char*)&Vlds[0][0] + c * 128;

  for (int kt = 0; kt < 16; ++kt) {
    __syncthreads();                     // prev compute done with LDS
    *(bf16x8*)lK = rk;
    if (vAct) *(bf16x8*)lV = rv;
    __syncthreads();
    // prefetch next tile (overlaps compute below)
    if (kt < 15) {
      gK += 64 * KPD; gV += 64;
      if (kReal) rk = *(const bf16x8*)gK;
      if (vReal) rv = *(const bf16x8*)gV;
    }

    // ---- S^T = K * Q^T : A-frag = Klds slot row (jt*16 + c), d-chunk g
    f32x4 p0, p1, p2, p3;
    __builtin_amdgcn_s_setprio(1);
    {
      f32x4 z = {};
#pragma unroll
      for (int jt = 0; jt < 4; ++jt) {
        const char* kr = kROb + jt * 2048;
        bf16x8 ak0 = *(const bf16x8*)(kr + ((g ^ sw) << 4));
        bf16x8 ak1 = {};
        if (g == 0) ak1 = *(const bf16x8*)(kr + ((4 ^ sw) << 4));
        f32x4 s = __builtin_amdgcn_mfma_f32_16x16x32_bf16(ak0, aq0, z, 0, 0, 0);
        s = __builtin_amdgcn_mfma_f32_16x16x32_bf16(ak1, aq1, s, 0, 0, 0);
        if (jt == 0) p0 = s; else if (jt == 1) p1 = s;
        else if (jt == 2) p2 = s; else p3 = s;
      }
    }
    __builtin_amdgcn_s_setprio(0);

    // ---- per-lane softmax (lane owns q-row c; partners at ^16, ^32)
    float vmax = fmaxf(fmaxf(fmaxf(p0[0], p0[1]), fmaxf(p0[2], p0[3])),
                       fmaxf(fmaxf(p1[0], p1[1]), fmaxf(p1[2], p1[3])));
    vmax = fmaxf(vmax, fmaxf(fmaxf(fmaxf(p2[0], p2[1]), fmaxf(p2[2], p2[3])),
                             fmaxf(fmaxf(p3[0], p3[1]), fmaxf(p3[2], p3[3]))));
    vmax = fmaxf(vmax, __shfl_xor(vmax, 16));
    vmax = fmaxf(vmax, __shfl_xor(vmax, 32));
    if (__any(vmax > m + 8.f)) {         // defer-max: rescale only on growth
      const float mn = fmaxf(m, vmax);
      const float al = exp2f(m - mn);
      m = mn; lsum *= al;
      o0 *= al; o1 *= al; o2 *= al;
    }
    float rs = 0.f;
#pragma unroll
    for (int r = 0; r < 4; ++r) { p0[r] = exp2f(p0[r] - m); rs += p0[r]; }
#pragma unroll
    for (int r = 0; r < 4; ++r) { p1[r] = exp2f(p1[r] - m); rs += p1[r]; }
#pragma unroll
    for (int r = 0; r < 4; ++r) { p2[r] = exp2f(p2[r] - m); rs += p2[r]; }
#pragma unroll
    for (int r = 0; r < 4; ++r) { p3[r] = exp2f(p3[r] - m); rs += p3[r]; }
    rs += __shfl_xor(rs, 16);
    rs += __shfl_xor(rs, 32);
    lsum += rs;

    // ---- pack P: lane's regs are already the PV B-fragment
    union { bf16x8 v; unsigned u[4]; } pb0, pb1;
    pb0.u[0] = cvtpk(p0[0], p0[1]); pb0.u[1] = cvtpk(p0[2], p0[3]);
    pb0.u[2] = cvtpk(p1[0], p1[1]); pb0.u[3] = cvtpk(p1[2], p1[3]);
    pb1.u[0] = cvtpk(p2[0], p2[1]); pb1.u[1] = cvtpk(p2[2], p2[3]);
    pb1.u[2] = cvtpk(p3[0], p3[1]); pb1.u[3] = cvtpk(p3[2], p3[3]);

    // ---- O^T += V^T * P^T  (A-frag = Vlds row d = dt*16+c, key chunk kc*4+g)
    __builtin_amdgcn_s_setprio(1);
    {
      bf16x8 av;
      av = *(const bf16x8*)(vROb + ((0 ^ sw) << 4));
      o0 = __builtin_amdgcn_mfma_f32_16x16x32_bf16(av, pb0.v, o0, 0, 0, 0);
      av = *(const bf16x8*)(vROb + 2048 + ((0 ^ sw) << 4) + ((g ^ sw) - (0 ^ sw)) * 0);
      // (recompute cleanly below)
      av = *(const bf16x8*)(vROb + ((g ^ sw) << 4));
      o0 = o0;  // no-op guard (see clean sequence)
      __builtin_amdgcn_s_setprio(0);
      // clean sequence:
      __builtin_amdgcn_s_setprio(1);
      av = *(const bf16x8*)(vROb + ((g ^ sw) << 4));
      o0 = __builtin_amdgcn_mfma_f32_16x16x32_bf16(av, pb0.v, (f32x4){}, 0, 0, 0);
    }
    __builtin_amdgcn_s_setprio(0);
    // NOTE: replaced below — see actual implementation
  }
}

// The above attn3 draft contained an editing error; the real kernel follows.
// ---------------------------------------------------------------------------
__global__ __launch_bounds__(512)
void attn4(const unsigned short* __restrict__ Qs,
           const unsigned short* __restrict__ Kp,
           const unsigned short* __restrict__ Vt,
           unsigned short* __restrict__ AO) {
  __shared__ unsigned short Klds[64][64];
  __shared__ unsigned short Vlds[48][64];

  const int tid = threadIdx.x;
  const int w = tid >> 6, l = tid & 63, g = l >> 4, c = l & 15;
  const int qt = blockIdx.x & 7, bh = blockIdx.x >> 3;
  const int b = bh >> 3, h = bh & 7;
  const int qrow0 = qt * 128 + w * 16;

  const int slot = tid >> 3, pc = tid & 7;
  const int lcK = pc ^ (slot & 7);
  const int key = (slot & 35) | ((slot & 12) << 1) | ((slot & 16) >> 2);
  const bool kReal = (lcK < 5);
  const unsigned short* gK = Kp + (size_t)((h << 10) + key) * KPD + lcK * 8;
  unsigned short* lK = &Klds[slot][pc * 8];
  const bool vAct = tid < 384;
  const int vrow = vAct ? slot : 0;
  const bool vReal = vAct && (slot < 40);
  const unsigned short* gV = Vt + (size_t)(h * KPD + vrow) * SEQ + (pc ^ (vrow & 7)) * 8;
  unsigned short* lV = &Vlds[vrow][pc * 8];

  const unsigned short* qp = Qs + (size_t)(b * SEQ + qrow0 + c) * CH + h * HD;
  bf16x8 aq0 = *(const bf16x8*)(qp + g * 8);
  bf16x8 aq1 = {};
  if (g == 0) aq1 = *(const bf16x8*)(qp + 32);

  f32x4 o0 = {}, o1 = {}, o2 = {};
  float m = -3e38f, lsum = 0.f;

  bf16x8 rk = {}, rv = {};
  if (kReal) rk = *(const bf16x8*)gK;
  if (vReal) rv = *(const bf16x8*)gV;

  const int sw = c & 7;
  const char* kROb = (const char*)&Klds[0][0] + c * 128;
  const char* vROb = (const char*)&Vlds[0][0] + c * 128;

  for (int kt = 0; kt < 16; ++kt) {
    __syncthreads();
    *(bf16x8*)lK = rk;
    if (vAct) *(bf16x8*)lV = rv;
    __syncthreads();
    if (kt < 15) {
      gK += 64 * KPD; gV += 64;
      if (kReal) rk = *(const bf16x8*)gK;
      if (vReal) rv = *(const bf16x8*)gV;
    }

    f32x4 p0, p1, p2, p3;
    __builtin_amdgcn_s_setprio(1);
    {
      f32x4 z = {};
#pragma unroll
      for (int jt = 0; jt < 4; ++jt) {
        const char* kr = kROb + jt * 2048;
        bf16x8 ak0 = *(const bf16x8*)(kr + ((g ^ sw) << 4));
        bf16x8 ak1 = {};
        if (g == 0) ak1 = *(const bf16x8*)(kr + ((4 ^ sw) << 4));
        f32x4 s = __builtin_amdgcn_mfma_f32_16x16x32_bf16(ak0, aq0, z, 0, 0, 0);
        s = __builtin_amdgcn_mfma_f32_16x16x32_bf16(ak1, aq1, s, 0, 0, 0);
        if (jt == 0) p0 = s; else if (jt == 1) p1 = s;
        else if (jt == 2) p2 = s; else p3 = s;
      }
    }
    __builtin_amdgcn_s_setprio(0);

    float vmax = fmaxf(fmaxf(fmaxf(p0[0], p0[1]), fmaxf(p0[2], p0[3])),
                       fmaxf(fmaxf(p1[0], p1[1]), fmaxf(p1[2], p1[3])));
    vmax = fmaxf(vmax, fmaxf(fmaxf(fmaxf(p2[0], p2[1]), fmaxf(p2[2], p2[3])),
                             fmaxf(fmaxf(p3[0], p3[1]), fmaxf(p3[2], p3[3]))));
    vmax = fmaxf(vmax, __shfl_xor(vmax, 16));
    vmax = fmaxf(vmax, __shfl_xor(vmax, 32));
    if (__any(vmax > m + 8.f)) {
      const float mn = fmaxf(m, vmax);
      const float al = exp2f(m - mn);
      m = mn; lsum *= al;
      o0 *= al; o1 *= al; o2 *= al;
    }
    float rs = 0.f;
#pragma unroll
    for (int r = 0; r < 4; ++r) { p0[r] = exp2f(p0[r] - m); rs += p0[r]; }
#pragma unroll
    for (int r = 0; r < 4; ++r) { p1[r] = exp2f(p1[r] - m); rs += p1[r]; }
#pragma unroll
    for (int r = 0; r < 4; ++r) { p2[r] = exp2f(p2[r] - m); rs += p2[r]; }
#pragma unroll
    for (int r = 0; r < 4; ++r) { p3[r] = exp2f(p3[r] - m); rs += p3[r]; }
    rs += __shfl_xor(rs, 16);
    rs += __shfl_xor(rs, 32);
    lsum += rs;

    union { bf16x8 v; unsigned u[4]; } pb0, pb1;
    pb0.u[0] = cvtpk(p0[0], p0[1]); pb0.u[1] = cvtpk(p0[2], p0[3]);
    pb0.u[2] = cvtpk(p1[0], p1[1]); pb0.u[3] = cvtpk(p1[2], p1[3]);
    pb1.u[0] = cvtpk(p2[0], p2[1]); pb1.u[1] = cvtpk(p2[2], p2[3]);
    pb1.u[2] = cvtpk(p3[0], p3[1]); pb1.u[3] = cvtpk(p3[2], p3[3]);

    __builtin_amdgcn_s_setprio(1);
    {
      bf16x8 av;
      av = *(const bf16x8*)(vROb + (((0 * 4 + g) ^ sw) << 4));
      o0 = __builtin_amdgcn_mfma_f32_16x16x32_bf16(av, pb0.v, o0, 0, 0, 0);
      av = *(const bf16x8*)(vROb + 2048 + (((0 * 4 + g) ^ sw) << 4));
      o1 = __builtin_amdgcn_mfma_f32_16x16x32_bf16(av, pb0.v, o1, 0, 0, 0);
      av = *(const bf16x8*)(vROb + 4096 + (((0 * 4 + g) ^ sw) << 4));
      o2 = __builtin_amdgcn_mfma_f32_16x16x32_bf16(av, pb0.v, o2, 0, 0, 0);
      av = *(const bf16x8*)(vROb + (((1 * 4 + g) ^ sw) << 4));
      o0 = __builtin_amdgcn_mfma_f32_16x16x32_bf16(av, pb1.v, o0, 0, 0, 0);
      av = *(const bf16x8*)(vROb + 2048 + (((1 * 4 + g) ^ sw) << 4));
      o1 = __builtin_amdgcn_mfma_f32_16x16x32_bf16(av, pb1.v, o1, 0, 0, 0);
      av = *(const bf16x8*)(vROb + 4096 + (((1 * 4 + g) ^ sw) << 4));
      o2 = __builtin_amdgcn_mfma_f32_16x16x32_bf16(av, pb1.v, o2, 0, 0, 0);
    }
    __builtin_amdgcn_s_setprio(0);
  }

  // ---- epilogue: lane owns q-row c; O^T row = d
  const float inv = 1.0f / lsum;
  unsigned short* orow = AO + (size_t)(b * SEQ + qrow0 + c) * CH + h * HD;
  union { uint2 q; unsigned u[2]; } st;
  st.u[0] = cvtpk(o0[0] * inv, o0[1] * inv);
  st.u[1] = cvtpk(o0[2] * inv, o0[3] * inv);
  *(uint2*)(orow + g * 4) = st.q;
  st.u[0] = cvtpk(o1[0] * inv, o1[1] * inv);
  st.u[1] = cvtpk(o1[2] * inv, o1[3] * inv);
  *(uint2*)(orow + 16 + g * 4) = st.q;
  if (g < 2) {
    st.u[0] = cvtpk(o2[0] * inv, o2[1] * inv);
    st.u[1] = cvtpk(o2[2] * inv, o2[3] * inv);
    *(uint2*)(orow + 32 + g * 4) = st.q;
  }
}

// ---------------------------------------------------------------------------
extern "C" void kernel_launch(void* const* d_in, const int* in_sizes, int n_in,
                              void* d_out, int out_size, void* d_ws, size_t ws_size,
                              hipStream_t stream) {
  const float* hs = (const float*)d_in[0];
  const float* Wq = (const float*)d_in[1];
  const float* Wk = (const float*)d_in[2];
  const float* Wv = (const float*)d_in[3];
  const float* Wo = (const float*)d_in[4];
  const float* bo = (const float*)d_in[5];
  const int* kptr = (const int*)d_in[7];
  float* out = (float*)d_out;

  unsigned short* hsb = (unsigned short*)d_ws;
  unsigned short* wqb = hsb + HS_N;
  unsigned short* wkb = wqb + W_N;
  unsigned short* wvb = wkb + W_N;
  unsigned short* wob = wvb + W_N;
  unsigned short* Qs  = wob + W_N;
  unsigned short* Kp  = Qs + HS_N;                 // [8][1024][48]
  unsigned short* Vt  = Kp + NH * SEQ * KPD;       // [8][48][1024]
  unsigned short* AO  = Vt + NH * KPD * SEQ;       // [16384][320]

  dim3 blk(256);
  cvt_kernel<<<dim3((HS_N + 4 * W_N) / 2048), blk, 0, stream>>>(
      hs, Wq, Wk, Wv, Wo, hsb, wqb, wkb, wvb, wob);
  proj3<0, 128><<<dim3(128, 5), blk, 0, stream>>>(hsb, wqb, Qs, nullptr, nullptr, nullptr, nullptr);
  proj3<1, 64><<<dim3(16, 5, 2), blk, 0, stream>>>(hsb, wkb, Kp, nullptr, kptr, wvb, Vt);
  attn4<<<dim3(1024), dim3(512), 0, stream>>>(Qs, Kp, Vt, AO);
  proj3<3, 128><<<dim3(128, 5), blk, 0, stream>>>(AO, wob, out, bo, nullptr, nullptr, nullptr);
}